// Round 8
// baseline (222.149 us; speedup 1.0000x reference)
//
#include <hip/hip_runtime.h>
#include <hip/hip_bf16.h>

#define N_ROWS   262144
#define LNKV_BLOCKS 1024
#define ATT_BLOCKS  1024
#define LN_EPS_F 1e-3f
#define EPS_W    1e-8f
#define NEPS_F   (262144.0f*1e-8f)

typedef __hip_bfloat16 bf16;
typedef short bf16x8 __attribute__((ext_vector_type(8)));
typedef float f32x4 __attribute__((ext_vector_type(4)));

__device__ __forceinline__ float bf2f(ushort u){ return __uint_as_float(((unsigned)u)<<16); }
__device__ __forceinline__ ushort f2bf(float f){
  unsigned u = __float_as_uint(f);
  unsigned r = (u + 0x7fffu + ((u>>16)&1u)) >> 16;
  return (ushort)r;
}
// single-instruction RNE pack of two f32 -> packed bf16x2
__device__ __forceinline__ unsigned cvtpk(float lo, float hi){
  unsigned r;
  asm("v_cvt_pk_bf16_f32 %0, %1, %2" : "=v"(r) : "v"(lo), "v"(hi));
  return r;
}

__device__ __forceinline__ float wave_sum64(float v){
#pragma unroll
  for (int off=1; off<64; off<<=1) v += __shfl_xor(v, off);
  return v;
}

// ---------------- LayerNorm(x) then KT=(xn@Wk)^T, VT=(xn@Wv)^T (bf16 [64][N]) via MFMA --------
// Transposed stores staged through padded LDS -> full-line coalesced global stores.
__global__ __launch_bounds__(256) void lnkv_kernel(
    const float* __restrict__ x, const float* __restrict__ gv, const float* __restrict__ bvec,
    const float* __restrict__ Wk, const float* __restrict__ Wv,
    ushort* __restrict__ KT, ushort* __restrict__ VT)
{
  __shared__ __align__(16) ushort wtab[2][8][64][8];      // 16 KB
  __shared__ __align__(16) ushort stg[32*264];            // 16.5 KB staging [col][256 rows + pad]
  __shared__ float bias_s[2][64];
  const int tid = threadIdx.x;
  const int w = tid >> 6, ln = tid & 63;
  const int lm = ln & 15, lg = ln >> 4;

  // one-time: gamma-folded bf16 fragment tables + bias rows
#pragma unroll
  for (int rep = 0; rep < 4; ++rep) {
    const int fg = w + rep*4;
    const int table = fg >> 3, f = fg & 7;
    const int kb = f >> 2, nj = f & 3;
    const float* __restrict__ W = table ? Wv : Wk;
    ushort vals[8];
#pragma unroll
    for (int i = 0; i < 8; ++i) {
      const int kk = kb*32 + lg*8 + i;
      vals[i] = f2bf(gv[kk] * W[kk*64 + nj*16 + lm]);
    }
    uint4 packed;
    packed.x = (unsigned)vals[0] | ((unsigned)vals[1] << 16);
    packed.y = (unsigned)vals[2] | ((unsigned)vals[3] << 16);
    packed.z = (unsigned)vals[4] | ((unsigned)vals[5] << 16);
    packed.w = (unsigned)vals[6] | ((unsigned)vals[7] << 16);
    *(uint4*)&wtab[table][f][ln][0] = packed;
  }
  if (tid < 128) {
    const int table = tid >> 6, cc = tid & 63;
    const float* __restrict__ W = table ? Wv : Wk;
    float a = 0.f;
#pragma unroll
    for (int c = 0; c < 64; ++c) a = fmaf(bvec[c], W[c*64+cc], a);
    bias_s[table][cc] = a;
  }
  __syncthreads();

  const size_t r0b = (size_t)blockIdx.x*256;   // block's 256-row span
  const size_t r0  = r0b + (size_t)w*64;       // wave's 64-row tile

  // ---- direct A-fragment loads + LN ----
  bf16x8 af[4][2];
#pragma unroll
  for (int mi = 0; mi < 4; ++mi){
    const float* xr = &x[(r0 + mi*16 + lm)*64 + lg*8];
    const float4 a0 = *(const float4*)xr;
    const float4 a1 = *(const float4*)(xr+4);
    const float4 b0 = *(const float4*)(xr+32);
    const float4 b1 = *(const float4*)(xr+36);
    float s1 = ((a0.x+a0.y)+(a0.z+a0.w)) + ((a1.x+a1.y)+(a1.z+a1.w))
             + ((b0.x+b0.y)+(b0.z+b0.w)) + ((b1.x+b1.y)+(b1.z+b1.w));
    float s2 = a0.x*a0.x; s2 = fmaf(a0.y,a0.y,s2); s2 = fmaf(a0.z,a0.z,s2); s2 = fmaf(a0.w,a0.w,s2);
    s2 = fmaf(a1.x,a1.x,s2); s2 = fmaf(a1.y,a1.y,s2); s2 = fmaf(a1.z,a1.z,s2); s2 = fmaf(a1.w,a1.w,s2);
    s2 = fmaf(b0.x,b0.x,s2); s2 = fmaf(b0.y,b0.y,s2); s2 = fmaf(b0.z,b0.z,s2); s2 = fmaf(b0.w,b0.w,s2);
    s2 = fmaf(b1.x,b1.x,s2); s2 = fmaf(b1.y,b1.y,s2); s2 = fmaf(b1.z,b1.z,s2); s2 = fmaf(b1.w,b1.w,s2);
    s1 += __shfl_xor(s1,16); s2 += __shfl_xor(s2,16);
    s1 += __shfl_xor(s1,32); s2 += __shfl_xor(s2,32);
    const float m  = s1*(1.0f/64.0f);
    const float rs = rsqrtf(s2*(1.0f/64.0f) - m*m + LN_EPS_F);
    const float nm = -m*rs;
    union { bf16x8 v; unsigned u[4]; } f0, f1;
    f0.u[0] = cvtpk(fmaf(a0.x,rs,nm), fmaf(a0.y,rs,nm));
    f0.u[1] = cvtpk(fmaf(a0.z,rs,nm), fmaf(a0.w,rs,nm));
    f0.u[2] = cvtpk(fmaf(a1.x,rs,nm), fmaf(a1.y,rs,nm));
    f0.u[3] = cvtpk(fmaf(a1.z,rs,nm), fmaf(a1.w,rs,nm));
    f1.u[0] = cvtpk(fmaf(b0.x,rs,nm), fmaf(b0.y,rs,nm));
    f1.u[1] = cvtpk(fmaf(b0.z,rs,nm), fmaf(b0.w,rs,nm));
    f1.u[2] = cvtpk(fmaf(b1.x,rs,nm), fmaf(b1.y,rs,nm));
    f1.u[3] = cvtpk(fmaf(b1.z,rs,nm), fmaf(b1.w,rs,nm));
    af[mi][0] = f0.v; af[mi][1] = f1.v;
  }

  // ---- K then V via MFMA; stage 32-col halves in LDS; coalesced transposed stores ----
  for (int table = 0; table < 2; ++table) {
    ushort* __restrict__ T = table ? VT : KT;
    for (int njh = 0; njh < 2; ++njh) {
      f32x4 acc[4][2];
#pragma unroll
      for (int mi = 0; mi < 4; ++mi)
#pragma unroll
        for (int n2 = 0; n2 < 2; ++n2) {
          const float bb = bias_s[table][(njh*2+n2)*16 + lm];
          f32x4 c; c[0]=bb; c[1]=bb; c[2]=bb; c[3]=bb;
          acc[mi][n2] = c;
        }
#pragma unroll
      for (int kb = 0; kb < 2; ++kb)
#pragma unroll
        for (int n2 = 0; n2 < 2; ++n2) {
          const bf16x8 bfrag = *(const bf16x8*)&wtab[table][kb*4 + njh*2 + n2][ln][0];
#pragma unroll
          for (int mi = 0; mi < 4; ++mi)
            acc[mi][n2] = __builtin_amdgcn_mfma_f32_16x16x32_bf16(af[mi][kb], bfrag, acc[mi][n2], 0,0,0);
        }
      __syncthreads();        // previous round's stg reads complete
#pragma unroll
      for (int mi = 0; mi < 4; ++mi)
#pragma unroll
        for (int n2 = 0; n2 < 2; ++n2){
          const int c  = n2*16 + lm;             // staging col 0..31
          const int ro = w*64 + mi*16 + lg*4;    // row within block span
          uint2 pk;
          pk.x = cvtpk(acc[mi][n2][0], acc[mi][n2][1]);
          pk.y = cvtpk(acc[mi][n2][2], acc[mi][n2][3]);
          *(uint2*)&stg[c*264 + ro] = pk;
        }
      __syncthreads();        // stg fully written
      {
        const int c = tid >> 3, pp = tid & 7;
        const size_t base = (size_t)(njh*32 + c)*N_ROWS + r0b;
#pragma unroll
        for (int k = 0; k < 4; ++k){
          const uint4 v = *(const uint4*)&stg[c*264 + k*64 + pp*8];
          *(uint4*)&T[base + k*64 + pp*8] = v;
        }
      }
    }
  }
}

// ---------------- one slot-attention data pass: 256 rows / block ----------------
__global__ __launch_bounds__(256) void attn_pass_kernel(
    const ushort* __restrict__ KT, const ushort* __restrict__ VT,
    const float* __restrict__ qT, float* __restrict__ pT,
    float* __restrict__ attn_out, int last)
{
  __shared__ __align__(16) ushort buf[64*256];   // 32 KB, XOR-swizzled 16-B chunks
  __shared__ __align__(16) uint2 attn_s[256];
  __shared__ __align__(16) float qs[256];
  const int tid = threadIdx.x;
  const int w = tid >> 6, ln = tid & 63;
  const int lm = ln & 15, lg = ln >> 4;
  qs[tid] = qT[tid];

  const size_t r0 = (size_t)blockIdx.x*256;

  // ---- stage VT tile into swizzled LDS: buf[d][chunk] ----
#pragma unroll
  for (int it = 0; it < 8; ++it){
    const int idx = tid + it*256;
    const int d = idx >> 5, ch = idx & 31;
    uint4 vv = *(const uint4*)&VT[(size_t)d*N_ROWS + r0 + ch*8];
    *(uint4*)&buf[d*256 + ((ch ^ (d&31))<<3)] = vv;
  }
  __syncthreads();

  // ---- logits: lane owns 4 rows, lg owns a 16-d slice; butterfly over lg ----
  const int lrow = w*64 + lm*4;
  float la[4][4];
#pragma unroll
  for (int r = 0; r < 4; ++r)
#pragma unroll
    for (int s = 0; s < 4; ++s) la[r][s] = 0.f;
#pragma unroll
  for (int dd = 0; dd < 16; ++dd){
    const int d = lg*16 + dd;
    const uint2 kk = *(const uint2*)&KT[(size_t)d*N_ROWS + r0 + lrow];
    const float k0 = bf2f((ushort)(kk.x & 0xffffu)), k1 = bf2f((ushort)(kk.x >> 16));
    const float k2 = bf2f((ushort)(kk.y & 0xffffu)), k3 = bf2f((ushort)(kk.y >> 16));
    const float4 q4 = *(const float4*)&qs[d*4];
#pragma unroll
    for (int s = 0; s < 4; ++s){
      const float qv = (s==0)?q4.x:(s==1)?q4.y:(s==2)?q4.z:q4.w;
      la[0][s] = fmaf(k0, qv, la[0][s]);
      la[1][s] = fmaf(k1, qv, la[1][s]);
      la[2][s] = fmaf(k2, qv, la[2][s]);
      la[3][s] = fmaf(k3, qv, la[3][s]);
    }
  }
#pragma unroll
  for (int r = 0; r < 4; ++r)
#pragma unroll
    for (int s = 0; s < 4; ++s){
      la[r][s] += __shfl_xor(la[r][s], 16);
      la[r][s] += __shfl_xor(la[r][s], 32);
    }

  // ---- softmax per row (lane-local; lg groups redundant) ----
  float av[4][4];
  float cs0=0.f, cs1=0.f, cs2=0.f, cs3=0.f;
#pragma unroll
  for (int r = 0; r < 4; ++r){
    const float mx = fmaxf(fmaxf(la[r][0],la[r][1]), fmaxf(la[r][2],la[r][3]));
    const float e0 = __expf(la[r][0]-mx), e1 = __expf(la[r][1]-mx);
    const float e2 = __expf(la[r][2]-mx), e3 = __expf(la[r][3]-mx);
    const float inv = 1.0f/((e0+e1)+(e2+e3));
    av[r][0]=e0*inv; av[r][1]=e1*inv; av[r][2]=e2*inv; av[r][3]=e3*inv;
    cs0 += av[r][0]; cs1 += av[r][1]; cs2 += av[r][2]; cs3 += av[r][3];
  }
  if (lg == 0){
#pragma unroll
    for (int r = 0; r < 4; ++r){
      uint2 pk;
      pk.x = cvtpk(av[r][0], av[r][1]);
      pk.y = cvtpk(av[r][2], av[r][3]);
      attn_s[lrow + r] = pk;
    }
    if (last){
#pragma unroll
      for (int s = 0; s < 4; ++s){
        float4 o; o.x=av[0][s]; o.y=av[1][s]; o.z=av[2][s]; o.w=av[3][s];
        *(float4*)&attn_out[(size_t)s*N_ROWS + r0 + lrow] = o;
      }
    }
  }
  // redundancy: 4 lg groups computed identical values -> scale by 1/4
  cs0 = wave_sum64(cs0)*0.25f; cs1 = wave_sum64(cs1)*0.25f;
  cs2 = wave_sum64(cs2)*0.25f; cs3 = wave_sum64(cs3)*0.25f;

  // ---- PV: thread = dim ln; wave w covers its own rows w*64..+63 ----
  float n0=0.f,n1=0.f,n2=0.f,n3=0.f, vs=0.f;
#pragma unroll
  for (int rb = 0; rb < 8; ++rb){
    const int ch = w*8 + rb;
    const uint4 vv = *(const uint4*)&buf[ln*256 + ((ch ^ (ln&31))<<3)];
    const ushort* vp = (const ushort*)&vv;
#pragma unroll
    for (int k2 = 0; k2 < 8; ++k2){
      const uint2 au = attn_s[ch*8 + k2];
      const float b0 = bf2f((ushort)(au.x & 0xffffu)), b1 = bf2f((ushort)(au.x >> 16));
      const float b2 = bf2f((ushort)(au.y & 0xffffu)), b3 = bf2f((ushort)(au.y >> 16));
      const float vvv = bf2f(vp[k2]);
      n0 = fmaf(b0, vvv, n0); n1 = fmaf(b1, vvv, n1);
      n2 = fmaf(b2, vvv, n2); n3 = fmaf(b3, vvv, n3);
      vs += vvv;
    }
  }

  // ---- block reduction, COALESCED partial writes pT[block][324] ----
  __syncthreads();
  float* fp = (float*)buf;
  fp[w*256 + 0*64 + ln] = n0;
  fp[w*256 + 1*64 + ln] = n1;
  fp[w*256 + 2*64 + ln] = n2;
  fp[w*256 + 3*64 + ln] = n3;
  fp[1024 + w*64 + ln] = vs;
  if (ln == 0){ fp[1280+w*4+0]=cs0; fp[1280+w*4+1]=cs1; fp[1280+w*4+2]=cs2; fp[1280+w*4+3]=cs3; }
  __syncthreads();
  const int tt = tid;
  float* pb = pT + (size_t)blockIdx.x*324;
  pb[tt] = fp[tt] + fp[256+tt] + fp[512+tt] + fp[768+tt];
  if (tt < 64)
    pb[256 + tt] = fp[1024+tt] + fp[1088+tt] + fp[1152+tt] + fp[1216+tt];
  if (tt < 4)
    pb[320 + tt] = fp[1280+tt] + fp[1284+tt] + fp[1288+tt] + fp[1292+tt];
}

// ---------------- slot update: 4 blocks x 512 threads, LDS-staged weights ----------------
__global__ __launch_bounds__(512) void update_kernel(int mode,
    const float* __restrict__ pT,
    float* __restrict__ slots, float* __restrict__ qT, float* __restrict__ out,
    const float* __restrict__ noise_fg, const float* __restrict__ noise_bg,
    const float* __restrict__ mu_fg, const float* __restrict__ ls_fg,
    const float* __restrict__ mu_bg, const float* __restrict__ ls_bg,
    const float* __restrict__ qfg_g, const float* __restrict__ qfg_b, const float* __restrict__ Wq_fg,
    const float* __restrict__ qbg_g, const float* __restrict__ qbg_b, const float* __restrict__ Wq_bg,
    const float* __restrict__ gfWx, const float* __restrict__ gfWh,
    const float* __restrict__ gfbin, const float* __restrict__ gfbrec,
    const float* __restrict__ gbWx, const float* __restrict__ gbWh,
    const float* __restrict__ gbbin, const float* __restrict__ gbbrec,
    const float* __restrict__ mfg_g, const float* __restrict__ mfg_b,
    const float* __restrict__ mfW1, const float* __restrict__ mfb1,
    const float* __restrict__ mfW2, const float* __restrict__ mfb2,
    const float* __restrict__ mbg_g, const float* __restrict__ mbg_b,
    const float* __restrict__ mbW1, const float* __restrict__ mbb1,
    const float* __restrict__ mbW2, const float* __restrict__ mbb2)
{
  const int j = blockIdx.x;          // slot 0..3 (0 = bg)
  const int tid = threadIdx.x;
  const int ln = tid & 63, wv = tid >> 6;
  const bool bg = (j == 0);

  __shared__ __align__(16) float wlds[24576];              // 96 KB
  __shared__ float bi_s[192], br_s[192], b1_s[128], b2_s[64];
  __shared__ float mg_s[64], mbv_s[64], qg_s[64], qb_s[64];
  __shared__ float u_s[64], h_s[64], hg_s[64], l_s[64], h1_s[128];
  __shared__ float gxp[2][192], ghp[2][192];
  __shared__ float pn_s[8][64], pv_s[8][64], csw[8];
  __shared__ float p4[4][128], p8[8][64];

  const float* __restrict__ Wx = bg?gbWx:gfWx;  const float* __restrict__ Wh = bg?gbWh:gfWh;
  const float* __restrict__ bi = bg?gbbin:gfbin; const float* __restrict__ br = bg?gbbrec:gfbrec;
  const float* __restrict__ W1 = bg?mbW1:mfW1;  const float* __restrict__ b1 = bg?mbb1:mfb1;
  const float* __restrict__ W2 = bg?mbW2:mfW2;  const float* __restrict__ b2 = bg?mbb2:mfb2;
  const float* __restrict__ Wq = bg?Wq_bg:Wq_fg;

  float hnew = 0.f;

  if (mode == 0) {
    { const float4* s = (const float4*)Wq; float4* d = (float4*)wlds;
#pragma unroll
      for (int i = 0; i < 2; ++i) d[tid + i*512] = s[tid + i*512]; }
    if (tid < 64){ qg_s[tid] = (bg?qbg_g:qfg_g)[tid]; qb_s[tid] = (bg?qbg_b:qfg_b)[tid]; }
    if (tid < 64) {
      hnew = bg ? fmaf(expf(ls_bg[tid]), noise_bg[tid], mu_bg[tid])
                : fmaf(expf(ls_fg[tid]), noise_fg[(j-1)*64+tid], mu_fg[tid]);
      slots[j*64 + tid] = hnew;
    }
    __syncthreads();
  } else {
    if (tid < 192){ bi_s[tid] = bi[tid]; br_s[tid] = br[tid]; }
    else if (tid < 320){ const int i2 = tid-192; b1_s[i2] = b1[i2]; }
    else if (tid < 384){ const int i2 = tid-320; b2_s[i2] = b2[i2]; }
    else if (tid < 448){ const int i2 = tid-384; mg_s[i2] = (bg?mbg_g:mfg_g)[i2]; mbv_s[i2] = (bg?mbg_b:mfg_b)[i2]; }
    else               { const int i2 = tid-448; qg_s[i2] = (bg?qbg_g:qfg_g)[i2]; qb_s[i2] = (bg?qbg_b:qfg_b)[i2]; }
    { const float4* sA = (const float4*)Wx; const float4* sB = (const float4*)Wh;
      float4* dA = (float4*)wlds; float4* dB = (float4*)(wlds + 12288);
#pragma unroll
      for (int i = 0; i < 6; ++i){ dA[tid + i*512] = sA[tid + i*512]; dB[tid + i*512] = sB[tid + i*512]; } }

    // ---- fused grid-reduce: coalesced reads of pT[block][324] ----
    {
      float a0 = 0.f, a1 = 0.f, a2 = 0.f;
      for (int b = wv; b < ATT_BLOCKS; b += 8){
        const float* pb = pT + (size_t)b*324;
        a0 += pb[j*64 + ln];      // numer for this slot
        a1 += pb[256 + ln];       // vsum
        a2 += pb[320 + j];        // colsum (wave-uniform scalar)
      }
      pn_s[wv][ln] = a0; pv_s[wv][ln] = a1;
      if (ln == 0) csw[wv] = a2;
    }
    if (tid < 64) h_s[tid] = slots[j*64 + tid];
    __syncthreads();
    if (tid < 64) {
      const float csum = ((csw[0]+csw[1])+(csw[2]+csw[3])) + ((csw[4]+csw[5])+(csw[6]+csw[7])) + NEPS_F;
      float nm = 0.f, vm = 0.f;
#pragma unroll
      for (int p2 = 0; p2 < 8; ++p2){ nm += pn_s[p2][tid]; vm += pv_s[p2][tid]; }
      u_s[tid] = (nm + EPS_W*vm) / csum;
    }
    __syncthreads();
    if (tid < 384) {
      const int gcol = tid % 192, gp = tid / 192;
      float ax = 0.f, ah = 0.f;
#pragma unroll
      for (int dd = 0; dd < 32; ++dd) {
        ax = fmaf(u_s[gp*32+dd], wlds[(gp*32+dd)*192 + gcol], ax);
        ah = fmaf(h_s[gp*32+dd], wlds[12288 + (gp*32+dd)*192 + gcol], ah);
      }
      gxp[gp][gcol] = ax; ghp[gp][gcol] = ah;
    }
    __syncthreads();
    { const float4* s1 = (const float4*)W1; const float4* s2 = (const float4*)W2; const float4* s3 = (const float4*)Wq;
      float4* d1 = (float4*)wlds; float4* d2 = (float4*)(wlds + 8192); float4* d3 = (float4*)(wlds + 16384);
#pragma unroll
      for (int i = 0; i < 4; ++i){ d1[tid + i*512] = s1[tid + i*512]; d2[tid + i*512] = s2[tid + i*512]; }
#pragma unroll
      for (int i = 0; i < 2; ++i){ d3[tid + i*512] = s3[tid + i*512]; } }
    if (tid < 64) {
      const float gx0 = gxp[0][tid]     + gxp[1][tid]     + bi_s[tid];
      const float gh0 = ghp[0][tid]     + ghp[1][tid]     + br_s[tid];
      const float gx1 = gxp[0][64+tid]  + gxp[1][64+tid]  + bi_s[64+tid];
      const float gh1 = ghp[0][64+tid]  + ghp[1][64+tid]  + br_s[64+tid];
      const float gx2 = gxp[0][128+tid] + gxp[1][128+tid] + bi_s[128+tid];
      const float gh2 = ghp[0][128+tid] + ghp[1][128+tid] + br_s[128+tid];
      const float h  = h_s[tid];
      const float z  = 1.f/(1.f + expf(-(gx0 + gh0)));
      const float rr = 1.f/(1.f + expf(-(gx1 + gh1)));
      const float hc = tanhf(gx2 + rr*gh2);
      const float hg = z*h + (1.f - z)*hc;
      hg_s[tid] = hg;
      const float m  = wave_sum64(hg) * (1.f/64.f);
      const float vr = wave_sum64((hg-m)*(hg-m)) * (1.f/64.f);
      const float rs = rsqrtf(vr + LN_EPS_F);
      l_s[tid] = mg_s[tid]*(hg-m)*rs + mbv_s[tid];
    }
    __syncthreads();
    { const int p4i = tid >> 7, hi = tid & 127;
      float a = 0.f;
#pragma unroll
      for (int dd = 0; dd < 16; ++dd) a = fmaf(l_s[p4i*16+dd], wlds[(p4i*16+dd)*128 + hi], a);
      p4[p4i][hi] = a;
    }
    __syncthreads();
    if (tid < 128) h1_s[tid] = fmaxf(((p4[0][tid]+p4[1][tid])+(p4[2][tid]+p4[3][tid])) + b1_s[tid], 0.f);
    __syncthreads();
    { const int p8i = tid >> 6;
      float a = 0.f;
#pragma unroll
      for (int dd = 0; dd < 16; ++dd) a = fmaf(h1_s[p8i*16+dd], wlds[8192 + (p8i*16+dd)*64 + ln], a);
      p8[p8i][ln] = a;
    }
    __syncthreads();
    if (tid < 64) {
      hnew = hg_s[tid] + b2_s[tid]
           + ((p8[0][tid]+p8[1][tid])+(p8[2][tid]+p8[3][tid]))
           + ((p8[4][tid]+p8[5][tid])+(p8[6][tid]+p8[7][tid]));
      slots[j*64 + tid] = hnew;
    }
  }

  if (mode == 3) {
    if (tid < 64) out[j*64 + tid] = hnew;
  } else {
    if (tid < 64) {
      const float m  = wave_sum64(hnew) * (1.f/64.f);
      const float vr = wave_sum64((hnew-m)*(hnew-m)) * (1.f/64.f);
      const float rs = rsqrtf(vr + LN_EPS_F);
      l_s[tid] = qg_s[tid]*(hnew-m)*rs + qb_s[tid];
    }
    __syncthreads();
    { const int p8i = tid >> 6;
      const float* __restrict__ WqL = (mode == 0) ? wlds : (wlds + 16384);
      float a = 0.f;
#pragma unroll
      for (int dd = 0; dd < 8; ++dd) a = fmaf(l_s[p8i*8+dd], WqL[(p8i*8+dd)*64 + ln], a);
      p8[p8i][ln] = a;
    }
    __syncthreads();
    if (tid < 64)
      qT[tid*4 + j] = (((p8[0][tid]+p8[1][tid])+(p8[2][tid]+p8[3][tid]))
                      +((p8[4][tid]+p8[5][tid])+(p8[6][tid]+p8[7][tid]))) * 0.125f;
  }
}

extern "C" void kernel_launch(void* const* d_in, const int* in_sizes, int n_in,
                              void* d_out, int out_size, void* d_ws, size_t ws_size,
                              hipStream_t stream)
{
  const float* x        = (const float*)d_in[0];
  const float* noise_fg = (const float*)d_in[1];
  const float* noise_bg = (const float*)d_in[2];
  const float* ln_g     = (const float*)d_in[3];
  const float* ln_b     = (const float*)d_in[4];
  const float* mu_fg    = (const float*)d_in[5];
  const float* ls_fg    = (const float*)d_in[6];
  const float* mu_bg    = (const float*)d_in[7];
  const float* ls_bg    = (const float*)d_in[8];
  const float* Wk       = (const float*)d_in[9];
  const float* Wv       = (const float*)d_in[10];
  const float* qfg_g    = (const float*)d_in[11];
  const float* qfg_b    = (const float*)d_in[12];
  const float* Wq_fg    = (const float*)d_in[13];
  const float* qbg_g    = (const float*)d_in[14];
  const float* qbg_b    = (const float*)d_in[15];
  const float* Wq_bg    = (const float*)d_in[16];
  const float* gfWx     = (const float*)d_in[17];
  const float* gfWh     = (const float*)d_in[18];
  const float* gfbin    = (const float*)d_in[19];
  const float* gfbrec   = (const float*)d_in[20];
  const float* gbWx     = (const float*)d_in[21];
  const float* gbWh     = (const float*)d_in[22];
  const float* gbbin    = (const float*)d_in[23];
  const float* gbbrec   = (const float*)d_in[24];
  const float* mfg_g    = (const float*)d_in[25];
  const float* mfg_b    = (const float*)d_in[26];
  const float* mfW1     = (const float*)d_in[27];
  const float* mfb1     = (const float*)d_in[28];
  const float* mfW2     = (const float*)d_in[29];
  const float* mfb2     = (const float*)d_in[30];
  const float* mbg_g    = (const float*)d_in[31];
  const float* mbg_b    = (const float*)d_in[32];
  const float* mbW1     = (const float*)d_in[33];
  const float* mbb1     = (const float*)d_in[34];
  const float* mbW2     = (const float*)d_in[35];
  const float* mbb2     = (const float*)d_in[36];

  float* out = (float*)d_out;

  // ws: KT bf16 (32MB) | VT bf16 (32MB) | slots(256) qT(256) | pT(1024*324)
  char* ws = (char*)d_ws;
  ushort* KT = (ushort*)ws;
  ushort* VT = (ushort*)(ws + (size_t)N_ROWS*64*2);
  float* fws   = (float*)(ws + (size_t)N_ROWS*64*4);
  float* slots = fws;
  float* qT    = fws + 256;
  float* pT    = fws + 512;

  auto launch_update = [&](int mode){
    update_kernel<<<4, 512, 0, stream>>>(mode, pT, slots, qT, out,
      noise_fg, noise_bg, mu_fg, ls_fg, mu_bg, ls_bg,
      qfg_g, qfg_b, Wq_fg, qbg_g, qbg_b, Wq_bg,
      gfWx, gfWh, gfbin, gfbrec, gbWx, gbWh, gbbin, gbbrec,
      mfg_g, mfg_b, mfW1, mfb1, mfW2, mfb2,
      mbg_g, mbg_b, mbW1, mbb1, mbW2, mbb2);
  };

  lnkv_kernel<<<LNKV_BLOCKS, 256, 0, stream>>>(x, ln_g, ln_b, Wk, Wv, KT, VT);
  launch_update(0);
  for (int it = 0; it < 3; ++it) {
    attn_pass_kernel<<<ATT_BLOCKS, 256, 0, stream>>>(KT, VT, qT, pT, out + 256, it==2 ? 1 : 0);
    launch_update(it+1);
  }
}

// Round 9
// 141.111 us; speedup vs baseline: 1.5743x; 1.5743x over previous
//
#include <hip/hip_runtime.h>
#include <hip/hip_bf16.h>

#define N_ROWS   262144
#define LNKV_BLOCKS 1024
#define ATT_BLOCKS  1024
#define LN_EPS_F 1e-3f
#define EPS_W    1e-8f
#define NEPS_F   (262144.0f*1e-8f)

typedef __hip_bfloat16 bf16;
typedef short bf16x8 __attribute__((ext_vector_type(8)));
typedef float f32x4 __attribute__((ext_vector_type(4)));

__device__ __forceinline__ float bf2f(ushort u){ return __uint_as_float(((unsigned)u)<<16); }
__device__ __forceinline__ ushort f2bf(float f){
  unsigned u = __float_as_uint(f);
  unsigned r = (u + 0x7fffu + ((u>>16)&1u)) >> 16;
  return (ushort)r;
}
// single-instruction RNE pack of two f32 -> packed bf16x2
__device__ __forceinline__ unsigned cvtpk(float lo, float hi){
  unsigned r;
  asm("v_cvt_pk_bf16_f32 %0, %1, %2" : "=v"(r) : "v"(lo), "v"(hi));
  return r;
}

__device__ __forceinline__ float wave_sum64(float v){
#pragma unroll
  for (int off=1; off<64; off<<=1) v += __shfl_xor(v, off);
  return v;
}

// ---------------- LayerNorm(x) then KT=(xn@Wk)^T, VT=(xn@Wv)^T (bf16 [64][N]) via MFMA --------
// Transposed stores staged through padded LDS -> full-line coalesced global stores.
__global__ __launch_bounds__(256) void lnkv_kernel(
    const float* __restrict__ x, const float* __restrict__ gv, const float* __restrict__ bvec,
    const float* __restrict__ Wk, const float* __restrict__ Wv,
    ushort* __restrict__ KT, ushort* __restrict__ VT)
{
  __shared__ __align__(16) ushort wtab[2][8][64][8];      // 16 KB
  __shared__ __align__(16) ushort stg[32*264];            // 16.5 KB staging [col][256 rows + pad]
  __shared__ float bias_s[2][64];
  const int tid = threadIdx.x;
  const int w = tid >> 6, ln = tid & 63;
  const int lm = ln & 15, lg = ln >> 4;

  // one-time: gamma-folded bf16 fragment tables + bias rows
#pragma unroll
  for (int rep = 0; rep < 4; ++rep) {
    const int fg = w + rep*4;
    const int table = fg >> 3, f = fg & 7;
    const int kb = f >> 2, nj = f & 3;
    const float* __restrict__ W = table ? Wv : Wk;
    ushort vals[8];
#pragma unroll
    for (int i = 0; i < 8; ++i) {
      const int kk = kb*32 + lg*8 + i;
      vals[i] = f2bf(gv[kk] * W[kk*64 + nj*16 + lm]);
    }
    uint4 packed;
    packed.x = (unsigned)vals[0] | ((unsigned)vals[1] << 16);
    packed.y = (unsigned)vals[2] | ((unsigned)vals[3] << 16);
    packed.z = (unsigned)vals[4] | ((unsigned)vals[5] << 16);
    packed.w = (unsigned)vals[6] | ((unsigned)vals[7] << 16);
    *(uint4*)&wtab[table][f][ln][0] = packed;
  }
  if (tid < 128) {
    const int table = tid >> 6, cc = tid & 63;
    const float* __restrict__ W = table ? Wv : Wk;
    float a = 0.f;
#pragma unroll
    for (int c = 0; c < 64; ++c) a = fmaf(bvec[c], W[c*64+cc], a);
    bias_s[table][cc] = a;
  }
  __syncthreads();

  const size_t r0b = (size_t)blockIdx.x*256;   // block's 256-row span
  const size_t r0  = r0b + (size_t)w*64;       // wave's 64-row tile

  // ---- direct A-fragment loads + LN ----
  bf16x8 af[4][2];
#pragma unroll
  for (int mi = 0; mi < 4; ++mi){
    const float* xr = &x[(r0 + mi*16 + lm)*64 + lg*8];
    const float4 a0 = *(const float4*)xr;
    const float4 a1 = *(const float4*)(xr+4);
    const float4 b0 = *(const float4*)(xr+32);
    const float4 b1 = *(const float4*)(xr+36);
    float s1 = ((a0.x+a0.y)+(a0.z+a0.w)) + ((a1.x+a1.y)+(a1.z+a1.w))
             + ((b0.x+b0.y)+(b0.z+b0.w)) + ((b1.x+b1.y)+(b1.z+b1.w));
    float s2 = a0.x*a0.x; s2 = fmaf(a0.y,a0.y,s2); s2 = fmaf(a0.z,a0.z,s2); s2 = fmaf(a0.w,a0.w,s2);
    s2 = fmaf(a1.x,a1.x,s2); s2 = fmaf(a1.y,a1.y,s2); s2 = fmaf(a1.z,a1.z,s2); s2 = fmaf(a1.w,a1.w,s2);
    s2 = fmaf(b0.x,b0.x,s2); s2 = fmaf(b0.y,b0.y,s2); s2 = fmaf(b0.z,b0.z,s2); s2 = fmaf(b0.w,b0.w,s2);
    s2 = fmaf(b1.x,b1.x,s2); s2 = fmaf(b1.y,b1.y,s2); s2 = fmaf(b1.z,b1.z,s2); s2 = fmaf(b1.w,b1.w,s2);
    s1 += __shfl_xor(s1,16); s2 += __shfl_xor(s2,16);
    s1 += __shfl_xor(s1,32); s2 += __shfl_xor(s2,32);
    const float m  = s1*(1.0f/64.0f);
    const float rs = rsqrtf(s2*(1.0f/64.0f) - m*m + LN_EPS_F);
    const float nm = -m*rs;
    union { bf16x8 v; unsigned u[4]; } f0, f1;
    f0.u[0] = cvtpk(fmaf(a0.x,rs,nm), fmaf(a0.y,rs,nm));
    f0.u[1] = cvtpk(fmaf(a0.z,rs,nm), fmaf(a0.w,rs,nm));
    f0.u[2] = cvtpk(fmaf(a1.x,rs,nm), fmaf(a1.y,rs,nm));
    f0.u[3] = cvtpk(fmaf(a1.z,rs,nm), fmaf(a1.w,rs,nm));
    f1.u[0] = cvtpk(fmaf(b0.x,rs,nm), fmaf(b0.y,rs,nm));
    f1.u[1] = cvtpk(fmaf(b0.z,rs,nm), fmaf(b0.w,rs,nm));
    f1.u[2] = cvtpk(fmaf(b1.x,rs,nm), fmaf(b1.y,rs,nm));
    f1.u[3] = cvtpk(fmaf(b1.z,rs,nm), fmaf(b1.w,rs,nm));
    af[mi][0] = f0.v; af[mi][1] = f1.v;
  }

  // ---- K then V via MFMA; stage 32-col halves in LDS; coalesced transposed stores ----
  for (int table = 0; table < 2; ++table) {
    ushort* __restrict__ T = table ? VT : KT;
    for (int njh = 0; njh < 2; ++njh) {
      f32x4 acc[4][2];
#pragma unroll
      for (int mi = 0; mi < 4; ++mi)
#pragma unroll
        for (int n2 = 0; n2 < 2; ++n2) {
          const float bb = bias_s[table][(njh*2+n2)*16 + lm];
          f32x4 c; c[0]=bb; c[1]=bb; c[2]=bb; c[3]=bb;
          acc[mi][n2] = c;
        }
#pragma unroll
      for (int kb = 0; kb < 2; ++kb)
#pragma unroll
        for (int n2 = 0; n2 < 2; ++n2) {
          const bf16x8 bfrag = *(const bf16x8*)&wtab[table][kb*4 + njh*2 + n2][ln][0];
#pragma unroll
          for (int mi = 0; mi < 4; ++mi)
            acc[mi][n2] = __builtin_amdgcn_mfma_f32_16x16x32_bf16(af[mi][kb], bfrag, acc[mi][n2], 0,0,0);
        }
      __syncthreads();        // previous round's stg reads complete
#pragma unroll
      for (int mi = 0; mi < 4; ++mi)
#pragma unroll
        for (int n2 = 0; n2 < 2; ++n2){
          const int c  = n2*16 + lm;             // staging col 0..31
          const int ro = w*64 + mi*16 + lg*4;    // row within block span
          uint2 pk;
          pk.x = cvtpk(acc[mi][n2][0], acc[mi][n2][1]);
          pk.y = cvtpk(acc[mi][n2][2], acc[mi][n2][3]);
          *(uint2*)&stg[c*264 + ro] = pk;
        }
      __syncthreads();        // stg fully written
      {
        const int c = tid >> 3, pp = tid & 7;
        const size_t base = (size_t)(njh*32 + c)*N_ROWS + r0b;
#pragma unroll
        for (int k = 0; k < 4; ++k){
          const uint4 v = *(const uint4*)&stg[c*264 + k*64 + pp*8];
          *(uint4*)&T[base + k*64 + pp*8] = v;
        }
      }
    }
  }
}

// ---------------- one slot-attention data pass: 256 rows / block ----------------
__global__ __launch_bounds__(256) void attn_pass_kernel(
    const ushort* __restrict__ KT, const ushort* __restrict__ VT,
    const float* __restrict__ qT, float* __restrict__ pT,
    float* __restrict__ attn_out, int last)
{
  __shared__ __align__(16) ushort buf[64*256];   // 32 KB, XOR-swizzled 16-B chunks
  __shared__ __align__(16) uint2 attn_s[256];
  __shared__ __align__(16) float qs[256];
  const int tid = threadIdx.x;
  const int w = tid >> 6, ln = tid & 63;
  const int lm = ln & 15, lg = ln >> 4;
  qs[tid] = qT[tid];

  const size_t r0 = (size_t)blockIdx.x*256;

  // ---- stage VT tile into swizzled LDS: buf[d][chunk] ----
#pragma unroll
  for (int it = 0; it < 8; ++it){
    const int idx = tid + it*256;
    const int d = idx >> 5, ch = idx & 31;
    uint4 vv = *(const uint4*)&VT[(size_t)d*N_ROWS + r0 + ch*8];
    *(uint4*)&buf[d*256 + ((ch ^ (d&31))<<3)] = vv;
  }
  __syncthreads();

  // ---- logits: lane owns 4 rows, lg owns a 16-d slice; butterfly over lg ----
  const int lrow = w*64 + lm*4;
  float la[4][4];
#pragma unroll
  for (int r = 0; r < 4; ++r)
#pragma unroll
    for (int s = 0; s < 4; ++s) la[r][s] = 0.f;
#pragma unroll
  for (int dd = 0; dd < 16; ++dd){
    const int d = lg*16 + dd;
    const uint2 kk = *(const uint2*)&KT[(size_t)d*N_ROWS + r0 + lrow];
    const float k0 = bf2f((ushort)(kk.x & 0xffffu)), k1 = bf2f((ushort)(kk.x >> 16));
    const float k2 = bf2f((ushort)(kk.y & 0xffffu)), k3 = bf2f((ushort)(kk.y >> 16));
    const float4 q4 = *(const float4*)&qs[d*4];
#pragma unroll
    for (int s = 0; s < 4; ++s){
      const float qv = (s==0)?q4.x:(s==1)?q4.y:(s==2)?q4.z:q4.w;
      la[0][s] = fmaf(k0, qv, la[0][s]);
      la[1][s] = fmaf(k1, qv, la[1][s]);
      la[2][s] = fmaf(k2, qv, la[2][s]);
      la[3][s] = fmaf(k3, qv, la[3][s]);
    }
  }
#pragma unroll
  for (int r = 0; r < 4; ++r)
#pragma unroll
    for (int s = 0; s < 4; ++s){
      la[r][s] += __shfl_xor(la[r][s], 16);
      la[r][s] += __shfl_xor(la[r][s], 32);
    }

  // ---- softmax per row (lane-local; lg groups redundant) ----
  float av[4][4];
  float cs0=0.f, cs1=0.f, cs2=0.f, cs3=0.f;
#pragma unroll
  for (int r = 0; r < 4; ++r){
    const float mx = fmaxf(fmaxf(la[r][0],la[r][1]), fmaxf(la[r][2],la[r][3]));
    const float e0 = __expf(la[r][0]-mx), e1 = __expf(la[r][1]-mx);
    const float e2 = __expf(la[r][2]-mx), e3 = __expf(la[r][3]-mx);
    const float inv = 1.0f/((e0+e1)+(e2+e3));
    av[r][0]=e0*inv; av[r][1]=e1*inv; av[r][2]=e2*inv; av[r][3]=e3*inv;
    cs0 += av[r][0]; cs1 += av[r][1]; cs2 += av[r][2]; cs3 += av[r][3];
  }
  if (lg == 0){
#pragma unroll
    for (int r = 0; r < 4; ++r){
      uint2 pk;
      pk.x = cvtpk(av[r][0], av[r][1]);
      pk.y = cvtpk(av[r][2], av[r][3]);
      attn_s[lrow + r] = pk;
    }
    if (last){
#pragma unroll
      for (int s = 0; s < 4; ++s){
        float4 o; o.x=av[0][s]; o.y=av[1][s]; o.z=av[2][s]; o.w=av[3][s];
        *(float4*)&attn_out[(size_t)s*N_ROWS + r0 + lrow] = o;
      }
    }
  }
  // redundancy: 4 lg groups computed identical values -> scale by 1/4
  cs0 = wave_sum64(cs0)*0.25f; cs1 = wave_sum64(cs1)*0.25f;
  cs2 = wave_sum64(cs2)*0.25f; cs3 = wave_sum64(cs3)*0.25f;

  // ---- PV: thread = dim ln; wave w covers its own rows w*64..+63 ----
  float n0=0.f,n1=0.f,n2=0.f,n3=0.f, vs=0.f;
#pragma unroll
  for (int rb = 0; rb < 8; ++rb){
    const int ch = w*8 + rb;
    const uint4 vv = *(const uint4*)&buf[ln*256 + ((ch ^ (ln&31))<<3)];
    const ushort* vp = (const ushort*)&vv;
#pragma unroll
    for (int k2 = 0; k2 < 8; ++k2){
      const uint2 au = attn_s[ch*8 + k2];
      const float b0 = bf2f((ushort)(au.x & 0xffffu)), b1 = bf2f((ushort)(au.x >> 16));
      const float b2 = bf2f((ushort)(au.y & 0xffffu)), b3 = bf2f((ushort)(au.y >> 16));
      const float vvv = bf2f(vp[k2]);
      n0 = fmaf(b0, vvv, n0); n1 = fmaf(b1, vvv, n1);
      n2 = fmaf(b2, vvv, n2); n3 = fmaf(b3, vvv, n3);
      vs += vvv;
    }
  }

  // ---- block reduction, COALESCED partial writes pT[block][324] ----
  __syncthreads();
  float* fp = (float*)buf;
  fp[w*256 + 0*64 + ln] = n0;
  fp[w*256 + 1*64 + ln] = n1;
  fp[w*256 + 2*64 + ln] = n2;
  fp[w*256 + 3*64 + ln] = n3;
  fp[1024 + w*64 + ln] = vs;
  if (ln == 0){ fp[1280+w*4+0]=cs0; fp[1280+w*4+1]=cs1; fp[1280+w*4+2]=cs2; fp[1280+w*4+3]=cs3; }
  __syncthreads();
  const int tt = tid;
  float* pb = pT + (size_t)blockIdx.x*324;
  pb[tt] = fp[tt] + fp[256+tt] + fp[512+tt] + fp[768+tt];
  if (tt < 64)
    pb[256 + tt] = fp[1024+tt] + fp[1088+tt] + fp[1152+tt] + fp[1216+tt];
  if (tt < 4)
    pb[320 + tt] = fp[1280+tt] + fp[1284+tt] + fp[1288+tt] + fp[1292+tt];
}

// ---------------- slot update: 4 blocks x 512 threads, LDS-staged weights ----------------
__global__ __launch_bounds__(512) void update_kernel(int mode,
    const float* __restrict__ pT,
    float* __restrict__ slots, float* __restrict__ qT, float* __restrict__ out,
    const float* __restrict__ noise_fg, const float* __restrict__ noise_bg,
    const float* __restrict__ mu_fg, const float* __restrict__ ls_fg,
    const float* __restrict__ mu_bg, const float* __restrict__ ls_bg,
    const float* __restrict__ qfg_g, const float* __restrict__ qfg_b, const float* __restrict__ Wq_fg,
    const float* __restrict__ qbg_g, const float* __restrict__ qbg_b, const float* __restrict__ Wq_bg,
    const float* __restrict__ gfWx, const float* __restrict__ gfWh,
    const float* __restrict__ gfbin, const float* __restrict__ gfbrec,
    const float* __restrict__ gbWx, const float* __restrict__ gbWh,
    const float* __restrict__ gbbin, const float* __restrict__ gbbrec,
    const float* __restrict__ mfg_g, const float* __restrict__ mfg_b,
    const float* __restrict__ mfW1, const float* __restrict__ mfb1,
    const float* __restrict__ mfW2, const float* __restrict__ mfb2,
    const float* __restrict__ mbg_g, const float* __restrict__ mbg_b,
    const float* __restrict__ mbW1, const float* __restrict__ mbb1,
    const float* __restrict__ mbW2, const float* __restrict__ mbb2)
{
  const int j = blockIdx.x;          // slot 0..3 (0 = bg)
  const int tid = threadIdx.x;
  const int ln = tid & 63, wv = tid >> 6;
  const bool bg = (j == 0);

  __shared__ __align__(16) float wlds[24576];              // 96 KB
  __shared__ float bi_s[192], br_s[192], b1_s[128], b2_s[64];
  __shared__ float mg_s[64], mbv_s[64], qg_s[64], qb_s[64];
  __shared__ float u_s[64], h_s[64], hg_s[64], l_s[64], h1_s[128];
  __shared__ float gxp[2][192], ghp[2][192];
  __shared__ float pn_s[8][64], pv_s[8][64], csw[8];
  __shared__ float p4[4][128], p8[8][64];

  const float* __restrict__ Wx = bg?gbWx:gfWx;  const float* __restrict__ Wh = bg?gbWh:gfWh;
  const float* __restrict__ bi = bg?gbbin:gfbin; const float* __restrict__ br = bg?gbbrec:gfbrec;
  const float* __restrict__ W1 = bg?mbW1:mfW1;  const float* __restrict__ b1 = bg?mbb1:mfb1;
  const float* __restrict__ W2 = bg?mbW2:mfW2;  const float* __restrict__ b2 = bg?mbb2:mfb2;
  const float* __restrict__ Wq = bg?Wq_bg:Wq_fg;

  float hnew = 0.f;

  if (mode == 0) {
    { const float4* s = (const float4*)Wq; float4* d = (float4*)wlds;
#pragma unroll
      for (int i = 0; i < 2; ++i) d[tid + i*512] = s[tid + i*512]; }
    if (tid < 64){ qg_s[tid] = (bg?qbg_g:qfg_g)[tid]; qb_s[tid] = (bg?qbg_b:qfg_b)[tid]; }
    if (tid < 64) {
      hnew = bg ? fmaf(expf(ls_bg[tid]), noise_bg[tid], mu_bg[tid])
                : fmaf(expf(ls_fg[tid]), noise_fg[(j-1)*64+tid], mu_fg[tid]);
      slots[j*64 + tid] = hnew;
    }
    __syncthreads();
  } else {
    if (tid < 192){ bi_s[tid] = bi[tid]; br_s[tid] = br[tid]; }
    else if (tid < 320){ const int i2 = tid-192; b1_s[i2] = b1[i2]; }
    else if (tid < 384){ const int i2 = tid-320; b2_s[i2] = b2[i2]; }
    else if (tid < 448){ const int i2 = tid-384; mg_s[i2] = (bg?mbg_g:mfg_g)[i2]; mbv_s[i2] = (bg?mbg_b:mfg_b)[i2]; }
    else               { const int i2 = tid-448; qg_s[i2] = (bg?qbg_g:qfg_g)[i2]; qb_s[i2] = (bg?qbg_b:qfg_b)[i2]; }
    { const float4* sA = (const float4*)Wx; const float4* sB = (const float4*)Wh;
      float4* dA = (float4*)wlds; float4* dB = (float4*)(wlds + 12288);
#pragma unroll
      for (int i = 0; i < 6; ++i){ dA[tid + i*512] = sA[tid + i*512]; dB[tid + i*512] = sB[tid + i*512]; } }

    // ---- fused grid-reduce: coalesced + deeply unrolled (48 loads in flight / wave) ----
    {
      float a0 = 0.f, a1 = 0.f, a2 = 0.f;
      float b0 = 0.f, b1v = 0.f, b2v = 0.f;
      for (int bb = 0; bb < ATT_BLOCKS/8; bb += 16){
#pragma unroll
        for (int u = 0; u < 16; u += 2){
          const float* pa = pT + (size_t)((bb+u  )*8 + wv)*324;
          const float* pb = pT + (size_t)((bb+u+1)*8 + wv)*324;
          a0 += pa[j*64 + ln];  a1 += pa[256 + ln];  a2 += pa[320 + j];
          b0 += pb[j*64 + ln];  b1v += pb[256 + ln]; b2v += pb[320 + j];
        }
      }
      pn_s[wv][ln] = a0 + b0; pv_s[wv][ln] = a1 + b1v;
      if (ln == 0) csw[wv] = a2 + b2v;
    }
    if (tid < 64) h_s[tid] = slots[j*64 + tid];
    __syncthreads();
    if (tid < 64) {
      const float csum = ((csw[0]+csw[1])+(csw[2]+csw[3])) + ((csw[4]+csw[5])+(csw[6]+csw[7])) + NEPS_F;
      float nm = 0.f, vm = 0.f;
#pragma unroll
      for (int p2 = 0; p2 < 8; ++p2){ nm += pn_s[p2][tid]; vm += pv_s[p2][tid]; }
      u_s[tid] = (nm + EPS_W*vm) / csum;
    }
    __syncthreads();
    if (tid < 384) {
      const int gcol = tid % 192, gp = tid / 192;
      float ax = 0.f, ah = 0.f;
#pragma unroll
      for (int dd = 0; dd < 32; ++dd) {
        ax = fmaf(u_s[gp*32+dd], wlds[(gp*32+dd)*192 + gcol], ax);
        ah = fmaf(h_s[gp*32+dd], wlds[12288 + (gp*32+dd)*192 + gcol], ah);
      }
      gxp[gp][gcol] = ax; ghp[gp][gcol] = ah;
    }
    __syncthreads();
    { const float4* s1 = (const float4*)W1; const float4* s2 = (const float4*)W2; const float4* s3 = (const float4*)Wq;
      float4* d1 = (float4*)wlds; float4* d2 = (float4*)(wlds + 8192); float4* d3 = (float4*)(wlds + 16384);
#pragma unroll
      for (int i = 0; i < 4; ++i){ d1[tid + i*512] = s1[tid + i*512]; d2[tid + i*512] = s2[tid + i*512]; }
#pragma unroll
      for (int i = 0; i < 2; ++i){ d3[tid + i*512] = s3[tid + i*512]; } }
    if (tid < 64) {
      const float gx0 = gxp[0][tid]     + gxp[1][tid]     + bi_s[tid];
      const float gh0 = ghp[0][tid]     + ghp[1][tid]     + br_s[tid];
      const float gx1 = gxp[0][64+tid]  + gxp[1][64+tid]  + bi_s[64+tid];
      const float gh1 = ghp[0][64+tid]  + ghp[1][64+tid]  + br_s[64+tid];
      const float gx2 = gxp[0][128+tid] + gxp[1][128+tid] + bi_s[128+tid];
      const float gh2 = ghp[0][128+tid] + ghp[1][128+tid] + br_s[128+tid];
      const float h  = h_s[tid];
      const float z  = 1.f/(1.f + expf(-(gx0 + gh0)));
      const float rr = 1.f/(1.f + expf(-(gx1 + gh1)));
      const float hc = tanhf(gx2 + rr*gh2);
      const float hg = z*h + (1.f - z)*hc;
      hg_s[tid] = hg;
      const float m  = wave_sum64(hg) * (1.f/64.f);
      const float vr = wave_sum64((hg-m)*(hg-m)) * (1.f/64.f);
      const float rs = rsqrtf(vr + LN_EPS_F);
      l_s[tid] = mg_s[tid]*(hg-m)*rs + mbv_s[tid];
    }
    __syncthreads();
    { const int p4i = tid >> 7, hi = tid & 127;
      float a = 0.f;
#pragma unroll
      for (int dd = 0; dd < 16; ++dd) a = fmaf(l_s[p4i*16+dd], wlds[(p4i*16+dd)*128 + hi], a);
      p4[p4i][hi] = a;
    }
    __syncthreads();
    if (tid < 128) h1_s[tid] = fmaxf(((p4[0][tid]+p4[1][tid])+(p4[2][tid]+p4[3][tid])) + b1_s[tid], 0.f);
    __syncthreads();
    { const int p8i = tid >> 6;
      float a = 0.f;
#pragma unroll
      for (int dd = 0; dd < 16; ++dd) a = fmaf(h1_s[p8i*16+dd], wlds[8192 + (p8i*16+dd)*64 + ln], a);
      p8[p8i][ln] = a;
    }
    __syncthreads();
    if (tid < 64) {
      hnew = hg_s[tid] + b2_s[tid]
           + ((p8[0][tid]+p8[1][tid])+(p8[2][tid]+p8[3][tid]))
           + ((p8[4][tid]+p8[5][tid])+(p8[6][tid]+p8[7][tid]));
      slots[j*64 + tid] = hnew;
    }
  }

  if (mode == 3) {
    if (tid < 64) out[j*64 + tid] = hnew;
  } else {
    if (tid < 64) {
      const float m  = wave_sum64(hnew) * (1.f/64.f);
      const float vr = wave_sum64((hnew-m)*(hnew-m)) * (1.f/64.f);
      const float rs = rsqrtf(vr + LN_EPS_F);
      l_s[tid] = qg_s[tid]*(hnew-m)*rs + qb_s[tid];
    }
    __syncthreads();
    { const int p8i = tid >> 6;
      const float* __restrict__ WqL = (mode == 0) ? wlds : (wlds + 16384);
      float a = 0.f;
#pragma unroll
      for (int dd = 0; dd < 8; ++dd) a = fmaf(l_s[p8i*8+dd], WqL[(p8i*8+dd)*64 + ln], a);
      p8[p8i][ln] = a;
    }
    __syncthreads();
    if (tid < 64)
      qT[tid*4 + j] = (((p8[0][tid]+p8[1][tid])+(p8[2][tid]+p8[3][tid]))
                      +((p8[4][tid]+p8[5][tid])+(p8[6][tid]+p8[7][tid]))) * 0.125f;
  }
}

extern "C" void kernel_launch(void* const* d_in, const int* in_sizes, int n_in,
                              void* d_out, int out_size, void* d_ws, size_t ws_size,
                              hipStream_t stream)
{
  const float* x        = (const float*)d_in[0];
  const float* noise_fg = (const float*)d_in[1];
  const float* noise_bg = (const float*)d_in[2];
  const float* ln_g     = (const float*)d_in[3];
  const float* ln_b     = (const float*)d_in[4];
  const float* mu_fg    = (const float*)d_in[5];
  const float* ls_fg    = (const float*)d_in[6];
  const float* mu_bg    = (const float*)d_in[7];
  const float* ls_bg    = (const float*)d_in[8];
  const float* Wk       = (const float*)d_in[9];
  const float* Wv       = (const float*)d_in[10];
  const float* qfg_g    = (const float*)d_in[11];
  const float* qfg_b    = (const float*)d_in[12];
  const float* Wq_fg    = (const float*)d_in[13];
  const float* qbg_g    = (const float*)d_in[14];
  const float* qbg_b    = (const float*)d_in[15];
  const float* Wq_bg    = (const float*)d_in[16];
  const float* gfWx     = (const float*)d_in[17];
  const float* gfWh     = (const float*)d_in[18];
  const float* gfbin    = (const float*)d_in[19];
  const float* gfbrec   = (const float*)d_in[20];
  const float* gbWx     = (const float*)d_in[21];
  const float* gbWh     = (const float*)d_in[22];
  const float* gbbin    = (const float*)d_in[23];
  const float* gbbrec   = (const float*)d_in[24];
  const float* mfg_g    = (const float*)d_in[25];
  const float* mfg_b    = (const float*)d_in[26];
  const float* mfW1     = (const float*)d_in[27];
  const float* mfb1     = (const float*)d_in[28];
  const float* mfW2     = (const float*)d_in[29];
  const float* mfb2     = (const float*)d_in[30];
  const float* mbg_g    = (const float*)d_in[31];
  const float* mbg_b    = (const float*)d_in[32];
  const float* mbW1     = (const float*)d_in[33];
  const float* mbb1     = (const float*)d_in[34];
  const float* mbW2     = (const float*)d_in[35];
  const float* mbb2     = (const float*)d_in[36];

  float* out = (float*)d_out;

  // ws: KT bf16 (32MB) | VT bf16 (32MB) | slots(256) qT(256) | pT(1024*324)
  char* ws = (char*)d_ws;
  ushort* KT = (ushort*)ws;
  ushort* VT = (ushort*)(ws + (size_t)N_ROWS*64*2);
  float* fws   = (float*)(ws + (size_t)N_ROWS*64*4);
  float* slots = fws;
  float* qT    = fws + 256;
  float* pT    = fws + 512;

  auto launch_update = [&](int mode){
    update_kernel<<<4, 512, 0, stream>>>(mode, pT, slots, qT, out,
      noise_fg, noise_bg, mu_fg, ls_fg, mu_bg, ls_bg,
      qfg_g, qfg_b, Wq_fg, qbg_g, qbg_b, Wq_bg,
      gfWx, gfWh, gfbin, gfbrec, gbWx, gbWh, gbbin, gbbrec,
      mfg_g, mfg_b, mfW1, mfb1, mfW2, mfb2,
      mbg_g, mbg_b, mbW1, mbb1, mbW2, mbb2);
  };

  lnkv_kernel<<<LNKV_BLOCKS, 256, 0, stream>>>(x, ln_g, ln_b, Wk, Wv, KT, VT);
  launch_update(0);
  for (int it = 0; it < 3; ++it) {
    attn_pass_kernel<<<ATT_BLOCKS, 256, 0, stream>>>(KT, VT, qT, pT, out + 256, it==2 ? 1 : 0);
    launch_update(it+1);
  }
}

// Round 10
// 109.678 us; speedup vs baseline: 2.0255x; 1.2866x over previous
//
#include <hip/hip_runtime.h>
#include <hip/hip_bf16.h>

#define N_ROWS   262144
#define TILES    1024
#define LN_EPS_F 1e-3f
#define EPS_W    1e-8f
#define NEPS_F   (262144.0f*1e-8f)

__device__ __forceinline__ float bf2f(unsigned u){ return __uint_as_float((u&0xffffu)<<16); }
__device__ __forceinline__ ushort f2bf(float f){
  unsigned u = __float_as_uint(f);
  return (ushort)((u + 0x7fffu + ((u>>16)&1u)) >> 16);
}
__device__ __forceinline__ unsigned cvtpk(float lo, float hi){
  unsigned r;
  asm("v_cvt_pk_bf16_f32 %0, %1, %2" : "=v"(r) : "v"(lo), "v"(hi));
  return r;
}
__device__ __forceinline__ float wave_sum64(float v){
#pragma unroll
  for (int off=1; off<64; off<<=1) v += __shfl_xor(v, off);
  return v;
}

// ---------- one slot-attention pass over x-hat (LN(x) pre-gamma/beta), K/V never materialized ----
// first=1: read x, do LN, build swizzled LDS tile + dump image to global xhat.
// else: linear reload of the tile image. Then logits = xhat . ucoef[d][j] + c_j, softmax,
// numer_j[d] = sum attn_j * xhat (x-space), block-reduce -> pT[block][324].
__global__ __launch_bounds__(256) void attn_pass_kernel(
    const float* __restrict__ x, uint* __restrict__ xhat,
    const float* __restrict__ ucoef, float* __restrict__ pT,
    float* __restrict__ attn_out, int first, int last)
{
  __shared__ __align__(16) ushort xs[64*256];     // 32 KB swizzled [d][row]
  __shared__ __align__(16) uint2 attn_s[256];
  __shared__ __align__(16) float qs[256];
  __shared__ float qc[4];
  const int tid = threadIdx.x;
  const int w = tid>>6, ln = tid&63;
  const int lm = ln&15, lg = ln>>4;
  qs[tid] = ucoef[tid];
  if (tid < 4) qc[tid] = ucoef[256+tid];

  const size_t r0 = (size_t)blockIdx.x*256;

  if (first){
    // ---- LN of 256 x rows; lane (lm,lg) owns row trow, d = lg*8..+7 and 32+lg*8..+7 ----
#pragma unroll
    for (int mi = 0; mi < 4; ++mi){
      const int trow = w*64 + mi*16 + lm;
      const float* xr = &x[(r0 + trow)*64 + lg*8];
      const float4 a0 = *(const float4*)xr;
      const float4 a1 = *(const float4*)(xr+4);
      const float4 b0 = *(const float4*)(xr+32);
      const float4 b1 = *(const float4*)(xr+36);
      float s1 = ((a0.x+a0.y)+(a0.z+a0.w)) + ((a1.x+a1.y)+(a1.z+a1.w))
               + ((b0.x+b0.y)+(b0.z+b0.w)) + ((b1.x+b1.y)+(b1.z+b1.w));
      float s2 = a0.x*a0.x; s2=fmaf(a0.y,a0.y,s2); s2=fmaf(a0.z,a0.z,s2); s2=fmaf(a0.w,a0.w,s2);
      s2=fmaf(a1.x,a1.x,s2); s2=fmaf(a1.y,a1.y,s2); s2=fmaf(a1.z,a1.z,s2); s2=fmaf(a1.w,a1.w,s2);
      s2=fmaf(b0.x,b0.x,s2); s2=fmaf(b0.y,b0.y,s2); s2=fmaf(b0.z,b0.z,s2); s2=fmaf(b0.w,b0.w,s2);
      s2=fmaf(b1.x,b1.x,s2); s2=fmaf(b1.y,b1.y,s2); s2=fmaf(b1.z,b1.z,s2); s2=fmaf(b1.w,b1.w,s2);
      s1 += __shfl_xor(s1,16); s2 += __shfl_xor(s2,16);
      s1 += __shfl_xor(s1,32); s2 += __shfl_xor(s2,32);
      const float m  = s1*(1.0f/64.0f);
      const float rs = rsqrtf(s2*(1.0f/64.0f) - m*m + LN_EPS_F);
      const float nm = -m*rs;
      float xv[16];
      xv[0]=fmaf(a0.x,rs,nm); xv[1]=fmaf(a0.y,rs,nm); xv[2]=fmaf(a0.z,rs,nm); xv[3]=fmaf(a0.w,rs,nm);
      xv[4]=fmaf(a1.x,rs,nm); xv[5]=fmaf(a1.y,rs,nm); xv[6]=fmaf(a1.z,rs,nm); xv[7]=fmaf(a1.w,rs,nm);
      xv[8]=fmaf(b0.x,rs,nm); xv[9]=fmaf(b0.y,rs,nm); xv[10]=fmaf(b0.z,rs,nm); xv[11]=fmaf(b0.w,rs,nm);
      xv[12]=fmaf(b1.x,rs,nm); xv[13]=fmaf(b1.y,rs,nm); xv[14]=fmaf(b1.z,rs,nm); xv[15]=fmaf(b1.w,rs,nm);
      const int ch = trow>>3, rr2 = trow&7;
#pragma unroll
      for (int p = 0; p < 8; ++p){
        const int d = lg*8 + p;
        xs[d*256 + ((ch ^ ((d*5)&31))<<3) + rr2] = (ushort)cvtpk(xv[p], xv[p]);
      }
#pragma unroll
      for (int p = 0; p < 8; ++p){
        const int d = 32 + lg*8 + p;
        xs[d*256 + ((ch ^ ((d*5)&31))<<3) + rr2] = (ushort)cvtpk(xv[8+p], xv[8+p]);
      }
    }
    __syncthreads();
    // dump swizzled image to global (linear, coalesced)
#pragma unroll
    for (int k = 0; k < 8; ++k){
      const int i = k*256 + tid;
      const uint4 v = *(const uint4*)&xs[i*8];
      *(uint4*)&xhat[(size_t)blockIdx.x*8192 + i*4] = v;
    }
  } else {
#pragma unroll
    for (int k = 0; k < 8; ++k){
      const int i = k*256 + tid;
      const uint4 v = *(const uint4*)&xhat[(size_t)blockIdx.x*8192 + i*4];
      *(uint4*)&xs[i*8] = v;
    }
    __syncthreads();
  }

  // ---- logits: lane owns rows lrow..+3, d-slice lg*16..+15; butterfly over lg ----
  const int lrow = w*64 + lm*4;
  float la[4][4];
#pragma unroll
  for (int r = 0; r < 4; ++r)
#pragma unroll
    for (int s = 0; s < 4; ++s) la[r][s] = 0.f;
#pragma unroll
  for (int dd = 0; dd < 16; ++dd){
    const int d = lg*16 + dd;
    const uint2 kk = *(const uint2*)&xs[d*256 + (((lrow>>3) ^ ((d*5)&31))<<3) + (lrow&7)];
    const float e0 = bf2f(kk.x), e1 = bf2f(kk.x>>16);
    const float e2 = bf2f(kk.y), e3 = bf2f(kk.y>>16);
    const float4 q4 = *(const float4*)&qs[d*4];
#pragma unroll
    for (int s = 0; s < 4; ++s){
      const float qv = (s==0)?q4.x:(s==1)?q4.y:(s==2)?q4.z:q4.w;
      la[0][s] = fmaf(e0, qv, la[0][s]);
      la[1][s] = fmaf(e1, qv, la[1][s]);
      la[2][s] = fmaf(e2, qv, la[2][s]);
      la[3][s] = fmaf(e3, qv, la[3][s]);
    }
  }
#pragma unroll
  for (int r = 0; r < 4; ++r)
#pragma unroll
    for (int s = 0; s < 4; ++s){
      la[r][s] += __shfl_xor(la[r][s], 16);
      la[r][s] += __shfl_xor(la[r][s], 32);
      la[r][s] += qc[s];
    }

  // ---- softmax per row ----
  float av[4][4];
  float cs0=0.f, cs1=0.f, cs2=0.f, cs3=0.f;
#pragma unroll
  for (int r = 0; r < 4; ++r){
    const float mx = fmaxf(fmaxf(la[r][0],la[r][1]), fmaxf(la[r][2],la[r][3]));
    const float e0 = __expf(la[r][0]-mx), e1 = __expf(la[r][1]-mx);
    const float e2 = __expf(la[r][2]-mx), e3 = __expf(la[r][3]-mx);
    const float inv = 1.0f/((e0+e1)+(e2+e3));
    av[r][0]=e0*inv; av[r][1]=e1*inv; av[r][2]=e2*inv; av[r][3]=e3*inv;
    cs0 += av[r][0]; cs1 += av[r][1]; cs2 += av[r][2]; cs3 += av[r][3];
  }
  if (lg == 0){
#pragma unroll
    for (int r = 0; r < 4; ++r){
      uint2 pk;
      pk.x = cvtpk(av[r][0], av[r][1]);
      pk.y = cvtpk(av[r][2], av[r][3]);
      attn_s[lrow + r] = pk;
    }
    if (last){
#pragma unroll
      for (int s = 0; s < 4; ++s){
        float4 o; o.x=av[0][s]; o.y=av[1][s]; o.z=av[2][s]; o.w=av[3][s];
        *(float4*)&attn_out[(size_t)s*N_ROWS + r0 + lrow] = o;
      }
    }
  }
  cs0 = wave_sum64(cs0)*0.25f; cs1 = wave_sum64(cs1)*0.25f;
  cs2 = wave_sum64(cs2)*0.25f; cs3 = wave_sum64(cs3)*0.25f;

  // ---- numer-hat: thread = dim ln over its wave's 64 rows ----
  float n0=0.f,n1=0.f,n2=0.f,n3=0.f, vs=0.f;
#pragma unroll
  for (int rb = 0; rb < 8; ++rb){
    const int ch = w*8 + rb;
    const uint4 vv = *(const uint4*)&xs[ln*256 + ((ch ^ ((ln*5)&31))<<3)];
    const ushort* vp = (const ushort*)&vv;
#pragma unroll
    for (int k2 = 0; k2 < 8; ++k2){
      const uint2 au = attn_s[ch*8 + k2];
      const float b0 = bf2f(au.x), b1 = bf2f(au.x>>16);
      const float b2 = bf2f(au.y), b3 = bf2f(au.y>>16);
      const float vvv = bf2f((unsigned)vp[k2]);
      n0 = fmaf(b0, vvv, n0); n1 = fmaf(b1, vvv, n1);
      n2 = fmaf(b2, vvv, n2); n3 = fmaf(b3, vvv, n3);
      vs += vvv;
    }
  }

  // ---- block reduction, coalesced pT[block][324] ----
  __syncthreads();
  float* fp = (float*)xs;
  fp[w*256 + 0*64 + ln] = n0;
  fp[w*256 + 1*64 + ln] = n1;
  fp[w*256 + 2*64 + ln] = n2;
  fp[w*256 + 3*64 + ln] = n3;
  fp[1024 + w*64 + ln] = vs;
  if (ln == 0){ fp[1280+w*4+0]=cs0; fp[1280+w*4+1]=cs1; fp[1280+w*4+2]=cs2; fp[1280+w*4+3]=cs3; }
  __syncthreads();
  float* pb = pT + (size_t)blockIdx.x*324;
  pb[tid] = fp[tid] + fp[256+tid] + fp[512+tid] + fp[768+tid];
  if (tid < 64)
    pb[256 + tid] = fp[1024+tid] + fp[1088+tid] + fp[1152+tid] + fp[1216+tid];
  if (tid < 4)
    pb[320 + tid] = fp[1280+tid] + fp[1284+tid] + fp[1288+tid] + fp[1292+tid];
}

// ---------------- slot update: 4 blocks x 512 threads ----------------
// Adds: updates = vin @ Wv (vin folds gamma/beta/EPS), and ucoef = g.(Wk q), c = b.(Wk q).
__global__ __launch_bounds__(512) void update_kernel(int mode,
    const float* __restrict__ pT,
    float* __restrict__ slots, float* __restrict__ ucoef, float* __restrict__ out,
    const float* __restrict__ noise_fg, const float* __restrict__ noise_bg,
    const float* __restrict__ mu_fg, const float* __restrict__ ls_fg,
    const float* __restrict__ mu_bg, const float* __restrict__ ls_bg,
    const float* __restrict__ ln_g, const float* __restrict__ ln_b,
    const float* __restrict__ Wk, const float* __restrict__ Wv,
    const float* __restrict__ qfg_g, const float* __restrict__ qfg_b, const float* __restrict__ Wq_fg,
    const float* __restrict__ qbg_g, const float* __restrict__ qbg_b, const float* __restrict__ Wq_bg,
    const float* __restrict__ gfWx, const float* __restrict__ gfWh,
    const float* __restrict__ gfbin, const float* __restrict__ gfbrec,
    const float* __restrict__ gbWx, const float* __restrict__ gbWh,
    const float* __restrict__ gbbin, const float* __restrict__ gbbrec,
    const float* __restrict__ mfg_g, const float* __restrict__ mfg_b,
    const float* __restrict__ mfW1, const float* __restrict__ mfb1,
    const float* __restrict__ mfW2, const float* __restrict__ mfb2,
    const float* __restrict__ mbg_g, const float* __restrict__ mbg_b,
    const float* __restrict__ mbW1, const float* __restrict__ mbb1,
    const float* __restrict__ mbW2, const float* __restrict__ mbb2)
{
  const int j = blockIdx.x;
  const int tid = threadIdx.x;
  const int ln = tid & 63, wv = tid >> 6;
  const bool bg = (j == 0);

  __shared__ __align__(16) float wlds[24640];
  __shared__ float bi_s[192], br_s[192], b1_s[128], b2_s[64];
  __shared__ float mg_s[64], mbv_s[64], qg_s[64], qb_s[64], gl_s[64], bl_s[64];
  __shared__ float vin_s[64], u_s[64], h_s[64], hg_s[64], l_s[64], h1_s[128], ql_s[64];
  __shared__ float gxp[2][192], ghp[2][192];
  __shared__ float pn_s[8][64], pv_s[8][64], csw[8];
  __shared__ float p4[4][128], p8[8][64];

  const float* __restrict__ Wx = bg?gbWx:gfWx;  const float* __restrict__ Wh = bg?gbWh:gfWh;
  const float* __restrict__ bi = bg?gbbin:gfbin; const float* __restrict__ br = bg?gbbrec:gfbrec;
  const float* __restrict__ W1 = bg?mbW1:mfW1;  const float* __restrict__ b1 = bg?mbb1:mfb1;
  const float* __restrict__ W2 = bg?mbW2:mfW2;  const float* __restrict__ b2 = bg?mbb2:mfb2;
  const float* __restrict__ Wq = bg?Wq_bg:Wq_fg;

  const int WQOFF  = (mode == 0) ? 0 : 16384;
  const int WKTOFF = (mode == 0) ? 4096 : 20480;

  float hnew = 0.f;

  if (mode == 0) {
    { const float4* s = (const float4*)Wq; float4* d = (float4*)wlds;
#pragma unroll
      for (int i = 0; i < 2; ++i) d[tid + i*512] = s[tid + i*512]; }
#pragma unroll
    for (int k = 0; k < 8; ++k){
      const int i = tid + k*512;
      wlds[4096 + (i&63)*65 + (i>>6)] = Wk[i];
    }
    if (tid < 64){
      qg_s[tid] = (bg?qbg_g:qfg_g)[tid]; qb_s[tid] = (bg?qbg_b:qfg_b)[tid];
      gl_s[tid] = ln_g[tid]; bl_s[tid] = ln_b[tid];
      hnew = bg ? fmaf(expf(ls_bg[tid]), noise_bg[tid], mu_bg[tid])
                : fmaf(expf(ls_fg[tid]), noise_fg[(j-1)*64+tid], mu_fg[tid]);
      slots[j*64 + tid] = hnew;
    }
    __syncthreads();
  } else {
    if (tid < 192){ bi_s[tid] = bi[tid]; br_s[tid] = br[tid]; }
    else if (tid < 320){ const int i2 = tid-192; b1_s[i2] = b1[i2]; }
    else if (tid < 384){ const int i2 = tid-320; b2_s[i2] = b2[i2]; }
    else if (tid < 448){ const int i2 = tid-384; mg_s[i2] = (bg?mbg_g:mfg_g)[i2]; mbv_s[i2] = (bg?mbg_b:mfg_b)[i2]; }
    else               { const int i2 = tid-448; qg_s[i2] = (bg?qbg_g:qfg_g)[i2]; qb_s[i2] = (bg?qbg_b:qfg_b)[i2]; }
    if (tid < 64){ gl_s[tid] = ln_g[tid]; bl_s[tid] = ln_b[tid]; }
    { const float4* sA = (const float4*)Wx; const float4* sB = (const float4*)Wh;
      float4* dA = (float4*)wlds; float4* dB = (float4*)(wlds + 12288);
#pragma unroll
      for (int i = 0; i < 6; ++i){ dA[tid + i*512] = sA[tid + i*512]; dB[tid + i*512] = sB[tid + i*512]; } }

    // ---- fused grid-reduce (deep unroll) ----
    {
      float a0 = 0.f, a1 = 0.f, a2 = 0.f;
      float c0 = 0.f, c1v = 0.f, c2v = 0.f;
      for (int bb = 0; bb < TILES/8; bb += 16){
#pragma unroll
        for (int u = 0; u < 16; u += 2){
          const float* pa = pT + (size_t)((bb+u  )*8 + wv)*324;
          const float* pc = pT + (size_t)((bb+u+1)*8 + wv)*324;
          a0 += pa[j*64 + ln];  a1 += pa[256 + ln];  a2 += pa[320 + j];
          c0 += pc[j*64 + ln];  c1v += pc[256 + ln]; c2v += pc[320 + j];
        }
      }
      pn_s[wv][ln] = a0 + c0; pv_s[wv][ln] = a1 + c1v;
      if (ln == 0) csw[wv] = a2 + c2v;
    }
    if (tid < 64) h_s[tid] = slots[j*64 + tid];
    __syncthreads();
    if (tid < 64) {
      const float csum = ((csw[0]+csw[1])+(csw[2]+csw[3])) + ((csw[4]+csw[5])+(csw[6]+csw[7])) + NEPS_F;
      float nm = 0.f, vm = 0.f;
#pragma unroll
      for (int p2 = 0; p2 < 8; ++p2){ nm += pn_s[p2][tid]; vm += pv_s[p2][tid]; }
      vin_s[tid] = gl_s[tid]*(nm + EPS_W*vm)/csum + bl_s[tid];
    }
    __syncthreads();
    // ---- updates = vin @ Wv ----
    { const int p8i = tid >> 6;
      float a = 0.f;
      float wbuf[8];
#pragma unroll
      for (int dd = 0; dd < 8; ++dd) wbuf[dd] = Wv[(p8i*8+dd)*64 + ln];
#pragma unroll
      for (int dd = 0; dd < 8; ++dd) a = fmaf(vin_s[p8i*8+dd], wbuf[dd], a);
      p8[p8i][ln] = a;
    }
    __syncthreads();
    if (tid < 64)
      u_s[tid] = ((p8[0][tid]+p8[1][tid])+(p8[2][tid]+p8[3][tid]))
               + ((p8[4][tid]+p8[5][tid])+(p8[6][tid]+p8[7][tid]));
    __syncthreads();
    // ---- GRU gates gemv (LDS weights) ----
    if (tid < 384) {
      const int gcol = tid % 192, gp = tid / 192;
      float ax = 0.f, ah = 0.f;
#pragma unroll
      for (int dd = 0; dd < 32; ++dd) {
        ax = fmaf(u_s[gp*32+dd], wlds[(gp*32+dd)*192 + gcol], ax);
        ah = fmaf(h_s[gp*32+dd], wlds[12288 + (gp*32+dd)*192 + gcol], ah);
      }
      gxp[gp][gcol] = ax; ghp[gp][gcol] = ah;
    }
    __syncthreads();
    // ---- stage B: W1, W2, Wq, WkT ----
    { const float4* s1 = (const float4*)W1; const float4* s2 = (const float4*)W2; const float4* s3 = (const float4*)Wq;
      float4* d1 = (float4*)wlds; float4* d2 = (float4*)(wlds + 8192); float4* d3 = (float4*)(wlds + 16384);
#pragma unroll
      for (int i = 0; i < 4; ++i){ d1[tid + i*512] = s1[tid + i*512]; d2[tid + i*512] = s2[tid + i*512]; }
#pragma unroll
      for (int i = 0; i < 2; ++i){ d3[tid + i*512] = s3[tid + i*512]; }
#pragma unroll
      for (int k = 0; k < 8; ++k){
        const int i = tid + k*512;
        wlds[20480 + (i&63)*65 + (i>>6)] = Wk[i];
      } }
    if (tid < 64) {
      const float gx0 = gxp[0][tid]     + gxp[1][tid]     + bi_s[tid];
      const float gh0 = ghp[0][tid]     + ghp[1][tid]     + br_s[tid];
      const float gx1 = gxp[0][64+tid]  + gxp[1][64+tid]  + bi_s[64+tid];
      const float gh1 = ghp[0][64+tid]  + ghp[1][64+tid]  + br_s[64+tid];
      const float gx2 = gxp[0][128+tid] + gxp[1][128+tid] + bi_s[128+tid];
      const float gh2 = ghp[0][128+tid] + ghp[1][128+tid] + br_s[128+tid];
      const float h  = h_s[tid];
      const float z  = 1.f/(1.f + expf(-(gx0 + gh0)));
      const float rr = 1.f/(1.f + expf(-(gx1 + gh1)));
      const float hc = tanhf(gx2 + rr*gh2);
      const float hg = z*h + (1.f - z)*hc;
      hg_s[tid] = hg;
      const float m  = wave_sum64(hg) * (1.f/64.f);
      const float vr = wave_sum64((hg-m)*(hg-m)) * (1.f/64.f);
      const float rs = rsqrtf(vr + LN_EPS_F);
      l_s[tid] = mg_s[tid]*(hg-m)*rs + mbv_s[tid];
    }
    __syncthreads();
    { const int p4i = tid >> 7, hi = tid & 127;
      float a = 0.f;
#pragma unroll
      for (int dd = 0; dd < 16; ++dd) a = fmaf(l_s[p4i*16+dd], wlds[(p4i*16+dd)*128 + hi], a);
      p4[p4i][hi] = a;
    }
    __syncthreads();
    if (tid < 128) h1_s[tid] = fmaxf(((p4[0][tid]+p4[1][tid])+(p4[2][tid]+p4[3][tid])) + b1_s[tid], 0.f);
    __syncthreads();
    { const int p8i = tid >> 6;
      float a = 0.f;
#pragma unroll
      for (int dd = 0; dd < 16; ++dd) a = fmaf(h1_s[p8i*16+dd], wlds[8192 + (p8i*16+dd)*64 + ln], a);
      p8[p8i][ln] = a;
    }
    __syncthreads();
    if (tid < 64) {
      hnew = hg_s[tid] + b2_s[tid]
           + ((p8[0][tid]+p8[1][tid])+(p8[2][tid]+p8[3][tid]))
           + ((p8[4][tid]+p8[5][tid])+(p8[6][tid]+p8[7][tid]));
      slots[j*64 + tid] = hnew;
    }
  }

  if (mode == 3) {
    if (tid < 64) out[j*64 + tid] = hnew;
  } else {
    // ---- q = LN(slots) @ Wq * scale ----
    if (tid < 64) {
      const float m  = wave_sum64(hnew) * (1.f/64.f);
      const float vr = wave_sum64((hnew-m)*(hnew-m)) * (1.f/64.f);
      const float rs = rsqrtf(vr + LN_EPS_F);
      l_s[tid] = qg_s[tid]*(hnew-m)*rs + qb_s[tid];
    }
    __syncthreads();
    { const int p8i = tid >> 6;
      float a = 0.f;
#pragma unroll
      for (int dd = 0; dd < 8; ++dd) a = fmaf(l_s[p8i*8+dd], wlds[WQOFF + (p8i*8+dd)*64 + ln], a);
      p8[p8i][ln] = a;
    }
    __syncthreads();
    if (tid < 64)
      ql_s[tid] = (((p8[0][tid]+p8[1][tid])+(p8[2][tid]+p8[3][tid]))
                  +((p8[4][tid]+p8[5][tid])+(p8[6][tid]+p8[7][tid]))) * 0.125f;
    __syncthreads();
    // ---- t = Wk @ q (from transposed LDS copy), ucoef = g.t, c = b.t ----
    if (tid < 256){
      const int d = tid & 63, pt = tid >> 6;
      float ts = 0.f;
#pragma unroll
      for (int oo = 0; oo < 16; ++oo){
        const int o = pt*16 + oo;
        ts = fmaf(wlds[WKTOFF + o*65 + d], ql_s[o], ts);
      }
      p8[pt][d] = ts;
    }
    __syncthreads();
    if (tid < 64){
      const float t = (p8[0][tid]+p8[1][tid]) + (p8[2][tid]+p8[3][tid]);
      ucoef[tid*4 + j] = gl_s[tid]*t;
      const float c = wave_sum64(bl_s[tid]*t);
      if (tid == 0) ucoef[256 + j] = c;
    }
  }
}

extern "C" void kernel_launch(void* const* d_in, const int* in_sizes, int n_in,
                              void* d_out, int out_size, void* d_ws, size_t ws_size,
                              hipStream_t stream)
{
  const float* x        = (const float*)d_in[0];
  const float* noise_fg = (const float*)d_in[1];
  const float* noise_bg = (const float*)d_in[2];
  const float* ln_g     = (const float*)d_in[3];
  const float* ln_b     = (const float*)d_in[4];
  const float* mu_fg    = (const float*)d_in[5];
  const float* ls_fg    = (const float*)d_in[6];
  const float* mu_bg    = (const float*)d_in[7];
  const float* ls_bg    = (const float*)d_in[8];
  const float* Wk       = (const float*)d_in[9];
  const float* Wv       = (const float*)d_in[10];
  const float* qfg_g    = (const float*)d_in[11];
  const float* qfg_b    = (const float*)d_in[12];
  const float* Wq_fg    = (const float*)d_in[13];
  const float* qbg_g    = (const float*)d_in[14];
  const float* qbg_b    = (const float*)d_in[15];
  const float* Wq_bg    = (const float*)d_in[16];
  const float* gfWx     = (const float*)d_in[17];
  const float* gfWh     = (const float*)d_in[18];
  const float* gfbin    = (const float*)d_in[19];
  const float* gfbrec   = (const float*)d_in[20];
  const float* gbWx     = (const float*)d_in[21];
  const float* gbWh     = (const float*)d_in[22];
  const float* gbbin    = (const float*)d_in[23];
  const float* gbbrec   = (const float*)d_in[24];
  const float* mfg_g    = (const float*)d_in[25];
  const float* mfg_b    = (const float*)d_in[26];
  const float* mfW1     = (const float*)d_in[27];
  const float* mfb1     = (const float*)d_in[28];
  const float* mfW2     = (const float*)d_in[29];
  const float* mfb2     = (const float*)d_in[30];
  const float* mbg_g    = (const float*)d_in[31];
  const float* mbg_b    = (const float*)d_in[32];
  const float* mbW1     = (const float*)d_in[33];
  const float* mbb1     = (const float*)d_in[34];
  const float* mbW2     = (const float*)d_in[35];
  const float* mbb2     = (const float*)d_in[36];

  float* out = (float*)d_out;

  // ws: xhat (32 MB swizzled tile images) | slots(256) | ucoef(512) | pT(1024*324)
  char* ws = (char*)d_ws;
  uint*  xhat  = (uint*)ws;
  float* fws   = (float*)(ws + (size_t)TILES*8192*4);
  float* slots = fws;
  float* ucoef = fws + 256;
  float* pT    = fws + 1024;

  auto launch_update = [&](int mode){
    update_kernel<<<4, 512, 0, stream>>>(mode, pT, slots, ucoef, out,
      noise_fg, noise_bg, mu_fg, ls_fg, mu_bg, ls_bg, ln_g, ln_b, Wk, Wv,
      qfg_g, qfg_b, Wq_fg, qbg_g, qbg_b, Wq_bg,
      gfWx, gfWh, gfbin, gfbrec, gbWx, gbWh, gbbin, gbbrec,
      mfg_g, mfg_b, mfW1, mfb1, mfW2, mfb2,
      mbg_g, mbg_b, mbW1, mbb1, mbW2, mbb2);
  };

  launch_update(0);
  for (int it = 0; it < 3; ++it) {
    attn_pass_kernel<<<TILES, 256, 0, stream>>>(x, xhat, ucoef, pT, out + 256,
                                                it==0 ? 1 : 0, it==2 ? 1 : 0);
    launch_update(it+1);
  }
}